// Round 6
// baseline (437.736 us; speedup 1.0000x reference)
//
#include <hip/hip_runtime.h>
#include <hip/hip_bf16.h>

// Problem constants
#define BATCH   1024
#define FDIM    2048
#define LDIM    80
#define EDIM    512
#define ODIM    2048
#define NEXP    8
#define INDIM   2560   // FDIM + EDIM

// GEMM geometry (8-phase 256^2 template)
#define BM      256
#define BN      256
#define BK      64
#define NKT     (INDIM / BK)   // 40 K-tiles

typedef __bf16 bf16x8 __attribute__((ext_vector_type(8)));
typedef float  f32x4  __attribute__((ext_vector_type(4)));

__device__ __forceinline__ unsigned int pack2(float lo, float hi) {
    __hip_bfloat162 h = __float22bfloat162_rn(make_float2(lo, hi));
    unsigned int u;
    __builtin_memcpy(&u, &h, 4);
    return u;
}
__device__ __forceinline__ float bf2f(unsigned short h) {
    return __uint_as_float((unsigned int)h << 16);
}
__device__ __forceinline__ void gload_lds16(const void* g, void* l) {
    __builtin_amdgcn_global_load_lds(
        (__attribute__((address_space(1))) void*)g,
        (__attribute__((address_space(3))) void*)l,
        16, 0, 0);
}

#define BAR()       __builtin_amdgcn_s_barrier()
#define SCHED_PIN() __builtin_amdgcn_sched_barrier(0)

// ---------------------------------------------------------------------------
// Kernel 0: W fp32 [e][k][o] -> Wb bf16 [e][o][k]  (unchanged, HBM-bound)
// ---------------------------------------------------------------------------
__global__ __launch_bounds__(256) void convert_w(
    const float* __restrict__ W, unsigned short* __restrict__ Wb)
{
    const int t  = threadIdx.x;
    const int o  = blockIdx.x * 256 + t;
    const int k0 = blockIdx.y * 32;
    const int e  = blockIdx.z;
    const float* src = W + (size_t)e * ((size_t)INDIM * ODIM) + (size_t)k0 * ODIM + o;
    unsigned int pk[16];
    #pragma unroll
    for (int j = 0; j < 16; ++j) {
        float a = src[(size_t)(2 * j) * ODIM];
        float b = src[(size_t)(2 * j + 1) * ODIM];
        pk[j] = pack2(a, b);
    }
    uint4* dst = (uint4*)(Wb + (size_t)e * ((size_t)ODIM * INDIM) + (size_t)o * INDIM + k0);
    dst[0] = make_uint4(pk[0],  pk[1],  pk[2],  pk[3]);
    dst[1] = make_uint4(pk[4],  pk[5],  pk[6],  pk[7]);
    dst[2] = make_uint4(pk[8],  pk[9],  pk[10], pk[11]);
    dst[3] = make_uint4(pk[12], pk[13], pk[14], pk[15]);
}

// ---------------------------------------------------------------------------
// Kernel 1: combined = [features | labels @ label_embed] as bf16 (unchanged)
// ---------------------------------------------------------------------------
__global__ __launch_bounds__(256) void prep_kernel(
    const float* __restrict__ features, const float* __restrict__ labels,
    const float* __restrict__ label_embed, unsigned short* __restrict__ cb)
{
    const int b0 = blockIdx.x * 4;
    const int t  = threadIdx.x;
    __shared__ float lab[4][LDIM];
    for (int idx = t; idx < 4 * LDIM; idx += 256) {
        lab[idx / LDIM][idx % LDIM] = labels[(size_t)(b0 + idx / LDIM) * LDIM + (idx % LDIM)];
    }
    __syncthreads();

    {
        const int r = t >> 6, c64 = t & 63;
        const float4* F4 = (const float4*)features;
        #pragma unroll
        for (int ch = 0; ch < 8; ++ch) {
            float4 v = F4[(size_t)(b0 + r) * (FDIM / 4) + c64 + 64 * ch];
            uint2 pk;
            pk.x = pack2(v.x, v.y);
            pk.y = pack2(v.z, v.w);
            *(uint2*)(cb + (size_t)(b0 + r) * INDIM + (size_t)(c64 + 64 * ch) * 4) = pk;
        }
    }
    {
        const int j = 2 * t;
        float acc[4][2] = {{0,0},{0,0},{0,0},{0,0}};
        const float2* le2 = (const float2*)label_embed;
        for (int l = 0; l < LDIM; ++l) {
            float2 le = le2[(size_t)l * (EDIM / 2) + t];
            #pragma unroll
            for (int r = 0; r < 4; ++r) {
                float lv = lab[r][l];
                acc[r][0] += lv * le.x;
                acc[r][1] += lv * le.y;
            }
        }
        #pragma unroll
        for (int r = 0; r < 4; ++r) {
            *(unsigned int*)(cb + (size_t)(b0 + r) * INDIM + FDIM + j) = pack2(acc[r][0], acc[r][1]);
        }
    }
}

// ---------------------------------------------------------------------------
// Kernel 2: gating = sigmoid(combined @ gate_w + gate_b)  (unchanged)
// ---------------------------------------------------------------------------
__global__ __launch_bounds__(256) void gate_kernel(
    const unsigned short* __restrict__ cb, const float* __restrict__ gw,
    const float* __restrict__ gb, float* __restrict__ gating)
{
    const int b = blockIdx.x, t = threadIdx.x;
    float p[NEXP] = {0,0,0,0,0,0,0,0};
    for (int i = t; i < INDIM; i += 256) {
        float c = bf2f(cb[(size_t)b * INDIM + i]);
        const float4* g4 = (const float4*)(gw + (size_t)i * NEXP);
        float4 u = g4[0], v = g4[1];
        p[0] += c * u.x; p[1] += c * u.y; p[2] += c * u.z; p[3] += c * u.w;
        p[4] += c * v.x; p[5] += c * v.y; p[6] += c * v.z; p[7] += c * v.w;
    }
    __shared__ float red[4][NEXP];
    const int lane = t & 63, wave = t >> 6;
    #pragma unroll
    for (int e = 0; e < NEXP; ++e) {
        float v = p[e];
        v += __shfl_down(v, 32); v += __shfl_down(v, 16); v += __shfl_down(v, 8);
        v += __shfl_down(v, 4);  v += __shfl_down(v, 2);  v += __shfl_down(v, 1);
        if (lane == 0) red[wave][e] = v;
    }
    __syncthreads();
    if (t < NEXP) {
        float s = red[0][t] + red[1][t] + red[2][t] + red[3][t] + gb[t];
        gating[(size_t)b * NEXP + t] = 1.0f / (1.0f + __expf(-s));
    }
}

// ---------------------------------------------------------------------------
// Kernel 3 (fast path): 256x256 8-phase pipelined MFMA GEMM.
// KEY CHANGE vs previous round: LDS is 4 NAMED __shared__ objects (As0/Bs0/
// As1/Bs1) instead of one smem[] blob, and the stage schedule never DMAs into
// a buffer while it is being read:
//   ph1: read cur (A-mh0, B-lower); stage ALL 4 A-quarters of T{kt+1} -> other-A
//   ph2: read cur (B-upper)
//   ph3: read cur (A-mh1)
//   ph4: stage ALL 4 B-quarters of T{kt+2} -> cur-B (B-reads ended at ph2);
//        counted s_waitcnt vmcnt(4) (keeps T{kt+2}-B in flight, drains
//        T{kt+1}-A issued 3 phases back).
// Why: LLVM's waitcnt pass aliases ds_reads against pending global_load_lds
// per underlying __shared__ OBJECT. With one blob, every phase's ds_read got a
// conservative wait-for-all-pending (the observed 2100cyc/phase drain, immune
// to barrier flavor). With named disjoint objects, reads of cur never alias
// pending DMAs (which target the other buffer), so no forced drains.
// ---------------------------------------------------------------------------
__global__ __launch_bounds__(512, 2) void moe_gemm8(
    const unsigned short* __restrict__ cb, const unsigned short* __restrict__ Wb,
    const float* __restrict__ gating, const float* __restrict__ eb,
    float* __restrict__ out)
{
    __shared__ unsigned short As0[256 * 64];   // 32 KiB each, 128 KiB total
    __shared__ unsigned short Bs0[256 * 64];
    __shared__ unsigned short As1[256 * 64];
    __shared__ unsigned short Bs1[256 * 64];

    const int t = threadIdx.x;
    const int lane = t & 63, wave = t >> 6;
    const int n0 = blockIdx.x * BN;
    const int m0 = blockIdx.y * BM;
    const int e  = blockIdx.z;

    const int wmi = wave >> 2;            // 0..1
    const int wni = wave & 3;             // 0..3
    const int wmBase = wmi * 128;
    const int wnBase = wni * 64;
    const int fm = lane & 15, fq = lane >> 4;
    const int fsw = fm & 7;               // row&7 for all fragment rows

    // staging source: thread t covers LDS row srow, physical chunk t&7;
    // pre-swizzle the GLOBAL chunk so LDS[row][pc] = global[row][pc ^ (row&7)]
    const int srow = t >> 3;                        // 0..63
    const int scn  = (t & 7) ^ (srow & 7);
    const size_t gOff = (size_t)srow * INDIM + (size_t)scn * 8;
    const unsigned short* aS = cb + (size_t)m0 * INDIM + gOff;
    const unsigned short* bS = Wb + (size_t)e * ((size_t)ODIM * INDIM)
                                  + (size_t)n0 * INDIM + gOff;

    // 4 quarters (64 rows each) of one 256x64 tile; dst is a NAMED array so the
    // waitcnt pass can prove non-aliasing against ds_reads of the other array.
    #define STAGE4_A(DST, kt) { _Pragma("unroll") for (int q = 0; q < 4; ++q) \
        gload_lds16(aS + (size_t)q * (64 * INDIM) + (size_t)(kt) * 64, (DST) + q * 4096 + wave * 512); }
    #define STAGE4_B(DST, kt) { _Pragma("unroll") for (int q = 0; q < 4; ++q) \
        gload_lds16(bS + (size_t)q * (64 * INDIM) + (size_t)(kt) * 64, (DST) + q * 4096 + wave * 512); }

    #define PH_READ_A(RA, base) { _Pragma("unroll") for (int mi = 0; mi < 4; ++mi) \
        _Pragma("unroll") for (int ks = 0; ks < 2; ++ks) \
            af[mi][ks] = *(const bf16x8*)((RA) + (wmBase + (base) + mi * 16 + fm) * 64 \
                                               + (((ks * 4 + fq) ^ fsw) * 8)); }
    #define PH_READ_B(BF, RB, base) { _Pragma("unroll") for (int ni = 0; ni < 2; ++ni) \
        _Pragma("unroll") for (int ks = 0; ks < 2; ++ks) \
            BF[ni][ks] = *(const bf16x8*)((RB) + (wnBase + (base) + ni * 16 + fm) * 64 \
                                               + (((ks * 4 + fq) ^ fsw) * 8)); }
    #define MFMA16(AI, AJ, BF) { __builtin_amdgcn_s_setprio(1); \
        _Pragma("unroll") for (int mi = 0; mi < 4; ++mi) \
        _Pragma("unroll") for (int ni = 0; ni < 2; ++ni) \
        _Pragma("unroll") for (int ks = 0; ks < 2; ++ks) \
            acc[(AI) + mi][(AJ) + ni] = __builtin_amdgcn_mfma_f32_16x16x32_bf16( \
                af[mi][ks], BF[ni][ks], acc[(AI) + mi][(AJ) + ni], 0, 0, 0); \
        __builtin_amdgcn_s_setprio(0); }

    f32x4 acc[8][4];
    #pragma unroll
    for (int i = 0; i < 8; ++i)
        #pragma unroll
        for (int j = 0; j < 4; ++j) acc[i][j] = (f32x4){0.f, 0.f, 0.f, 0.f};

    bf16x8 af[4][2], bA[2][2], bB[2][2];

    // Prologue: T0 fully -> As0/Bs0 (8), T1's B -> Bs1 (4).
    STAGE4_A(As0, 0); STAGE4_B(Bs0, 0); STAGE4_B(Bs1, 1);
    asm volatile("s_waitcnt vmcnt(4)");   // T0 resident; T1-B stays in flight
    BAR(); SCHED_PIN();

    // Per tile kt (read RA/RB, other-A = OA):
    //   T{kt}-A staged at (kt-1).ph1 -> landed by end-of-(kt-1) vmcnt(4)
    //   T{kt}-B staged at (kt-2).ph4 -> even older
    #define TILE(kt, RA, RB, OA) { \
        /* phase 1: C(mh0,nh0) */ \
        PH_READ_A(RA, 0); \
        PH_READ_B(bA, RB, 0); \
        if ((kt) + 1 < NKT) STAGE4_A(OA, (kt) + 1); \
        BAR(); \
        MFMA16(0, 0, bA); \
        SCHED_PIN(); BAR(); SCHED_PIN(); \
        /* phase 2: C(mh0,nh1) */ \
        PH_READ_B(bB, RB, 32); \
        BAR(); \
        MFMA16(0, 2, bB); \
        SCHED_PIN(); BAR(); SCHED_PIN(); \
        /* phase 3: C(mh1,nh1) */ \
        PH_READ_A(RA, 64); \
        BAR(); \
        MFMA16(4, 2, bB); \
        SCHED_PIN(); BAR(); SCHED_PIN(); \
        /* phase 4: C(mh1,nh0); stage next-next B into cur-B (reads done ph2) */ \
        if ((kt) + 2 < NKT) STAGE4_B(RB, (kt) + 2); \
        BAR(); \
        MFMA16(4, 0, bA); \
        SCHED_PIN(); \
        if ((kt) + 2 < NKT) { asm volatile("s_waitcnt vmcnt(4)"); } \
        else                { asm volatile("s_waitcnt vmcnt(0)"); } \
        BAR(); SCHED_PIN(); \
    }

    for (int kt = 0; kt < NKT; kt += 2) {
        TILE(kt,     As0, Bs0, As1);
        TILE(kt + 1, As1, Bs1, As0);
    }
    #undef TILE
    #undef STAGE4_A
    #undef STAGE4_B
    #undef PH_READ_A
    #undef PH_READ_B
    #undef MFMA16

    // Epilogue: gate-scale + gated bias, atomic combine over experts
    #pragma unroll
    for (int mi = 0; mi < 8; ++mi) {
        const int grow = m0 + wmBase + mi * 16 + fq * 4;
        const float g0 = gating[(size_t)(grow + 0) * NEXP + e];
        const float g1 = gating[(size_t)(grow + 1) * NEXP + e];
        const float g2 = gating[(size_t)(grow + 2) * NEXP + e];
        const float g3 = gating[(size_t)(grow + 3) * NEXP + e];
        #pragma unroll
        for (int ni = 0; ni < 4; ++ni) {
            const int gcol = n0 + wnBase + ni * 16 + fm;
            const float bias = eb[(size_t)e * ODIM + gcol];
            f32x4 a = acc[mi][ni];
            unsafeAtomicAdd(out + (size_t)(grow + 0) * ODIM + gcol, g0 * (a.x + bias));
            unsafeAtomicAdd(out + (size_t)(grow + 1) * ODIM + gcol, g1 * (a.y + bias));
            unsafeAtomicAdd(out + (size_t)(grow + 2) * ODIM + gcol, g2 * (a.z + bias));
            unsafeAtomicAdd(out + (size_t)(grow + 3) * ODIM + gcol, g3 * (a.w + bias));
        }
    }
}

// ---------------------------------------------------------------------------
// Kernel 3 (fallback, small-ws): in-loop fp32->bf16 W staging (unchanged)
// ---------------------------------------------------------------------------
__global__ __launch_bounds__(256) void moe_gemm_slow(
    const unsigned short* __restrict__ cb, const float* __restrict__ W,
    const float* __restrict__ gating, const float* __restrict__ eb,
    float* __restrict__ out)
{
    __shared__ unsigned short As[128 * 32];
    __shared__ unsigned short Bs[128 * 32];

    const int t = threadIdx.x;
    const int lane = t & 63, wave = t >> 6;
    const int n0 = blockIdx.x * 128;
    const int m0 = blockIdx.y * 128;
    const int e  = blockIdx.z;

    f32x4 acc[4][4];
    #pragma unroll
    for (int i = 0; i < 4; ++i)
        #pragma unroll
        for (int j = 0; j < 4; ++j) acc[i][j] = (f32x4){0.f, 0.f, 0.f, 0.f};

    const int arow = t >> 2, acg = t & 3;
    const unsigned short* ag0 = cb + (size_t)(m0 + arow) * INDIM + acg * 8;
    unsigned short* al0 = As + wave * 512;
    unsigned short* al1 = As + 2048 + wave * 512;

    const int bg = t & 15;
    const int bu = t >> 4;
    const float* wg = W + (size_t)e * ((size_t)INDIM * ODIM) + (size_t)(2 * bg) * ODIM + n0 + bu * 8;
    unsigned int* bl = (unsigned int*)Bs + bg + bu * 128;

    const int fm = lane & 15, fq = lane >> 4;
    const int wn = (wave & 1) * 64;
    const int wm = (wave >> 1) * 64;

    for (int k0 = 0; k0 < INDIM; k0 += 32) {
        __syncthreads();
        gload_lds16(ag0 + k0, al0);
        gload_lds16(ag0 + (size_t)64 * INDIM + k0, al1);
        const float* wp = wg + (size_t)k0 * ODIM;
        float4 r0a = *(const float4*)(wp);
        float4 r0b = *(const float4*)(wp + 4);
        float4 r1a = *(const float4*)(wp + ODIM);
        float4 r1b = *(const float4*)(wp + ODIM + 4);
        bl[0 * 16] = pack2(r0a.x, r1a.x);
        bl[1 * 16] = pack2(r0a.y, r1a.y);
        bl[2 * 16] = pack2(r0a.z, r1a.z);
        bl[3 * 16] = pack2(r0a.w, r1a.w);
        bl[4 * 16] = pack2(r0b.x, r1b.x);
        bl[5 * 16] = pack2(r0b.y, r1b.y);
        bl[6 * 16] = pack2(r0b.z, r1b.z);
        bl[7 * 16] = pack2(r0b.w, r1b.w);
        __syncthreads();

        bf16x8 af[4], bfr[4];
        #pragma unroll
        for (int mi = 0; mi < 4; ++mi)
            af[mi] = *(const bf16x8*)(As + (wm + mi * 16 + fm) * 32 + fq * 8);
        #pragma unroll
        for (int ni = 0; ni < 4; ++ni)
            bfr[ni] = *(const bf16x8*)(Bs + (wn + ni * 16 + fm) * 32 + fq * 8);
        #pragma unroll
        for (int mi = 0; mi < 4; ++mi)
            #pragma unroll
            for (int ni = 0; ni < 4; ++ni)
                acc[mi][ni] = __builtin_amdgcn_mfma_f32_16x16x32_bf16(af[mi], bfr[ni], acc[mi][ni], 0, 0, 0);
    }

    #pragma unroll
    for (int mi = 0; mi < 4; ++mi) {
        const int grow = m0 + wm + mi * 16 + fq * 4;
        const float g0 = gating[(size_t)(grow + 0) * NEXP + e];
        const float g1 = gating[(size_t)(grow + 1) * NEXP + e];
        const float g2 = gating[(size_t)(grow + 2) * NEXP + e];
        const float g3 = gating[(size_t)(grow + 3) * NEXP + e];
        #pragma unroll
        for (int ni = 0; ni < 4; ++ni) {
            const int gcol = n0 + wn + ni * 16 + fm;
            const float bias = eb[(size_t)e * ODIM + gcol];
            f32x4 a = acc[mi][ni];
            unsafeAtomicAdd(out + (size_t)(grow + 0) * ODIM + gcol, g0 * (a.x + bias));
            unsafeAtomicAdd(out + (size_t)(grow + 1) * ODIM + gcol, g1 * (a.y + bias));
            unsafeAtomicAdd(out + (size_t)(grow + 2) * ODIM + gcol, g2 * (a.z + bias));
            unsafeAtomicAdd(out + (size_t)(grow + 3) * ODIM + gcol, g3 * (a.w + bias));
        }
    }
}

// ---------------------------------------------------------------------------
extern "C" void kernel_launch(void* const* d_in, const int* in_sizes, int n_in,
                              void* d_out, int out_size, void* d_ws, size_t ws_size,
                              hipStream_t stream) {
    const float* features    = (const float*)d_in[0];
    const float* labels      = (const float*)d_in[1];
    const float* label_embed = (const float*)d_in[2];
    const float* gate_w      = (const float*)d_in[3];
    const float* gate_b      = (const float*)d_in[4];
    const float* expert_w    = (const float*)d_in[5];
    const float* expert_b    = (const float*)d_in[6];
    float* out = (float*)d_out;

    // ws layout: Wb bf16 [8][2048][2560] | cb bf16 [1024][2560] | gating f32
    const size_t wb_bytes = (size_t)NEXP * ODIM * INDIM * 2;        // 83,886,080
    const size_t cb_bytes = (size_t)BATCH * INDIM * 2;              //  5,242,880
    const size_t gt_bytes = (size_t)BATCH * NEXP * 4;               //     32,768
    const bool fast = ws_size >= wb_bytes + cb_bytes + gt_bytes;

    hipMemsetAsync(d_out, 0, (size_t)BATCH * ODIM * sizeof(float), stream);

    if (fast) {
        unsigned short* Wb = (unsigned short*)d_ws;
        unsigned short* cb = (unsigned short*)((char*)d_ws + wb_bytes);
        float* gating = (float*)((char*)d_ws + wb_bytes + cb_bytes);
        convert_w<<<dim3(ODIM / 256, INDIM / 32, NEXP), 256, 0, stream>>>(expert_w, Wb);
        prep_kernel<<<BATCH / 4, 256, 0, stream>>>(features, labels, label_embed, cb);
        gate_kernel<<<BATCH, 256, 0, stream>>>(cb, gate_w, gate_b, gating);
        moe_gemm8<<<dim3(ODIM / BN, BATCH / BM, NEXP), 512, 0, stream>>>(cb, Wb, gating, expert_b, out);
    } else {
        unsigned short* cb = (unsigned short*)d_ws;
        float* gating = (float*)((char*)d_ws + cb_bytes);
        prep_kernel<<<BATCH / 4, 256, 0, stream>>>(features, labels, label_embed, cb);
        gate_kernel<<<BATCH, 256, 0, stream>>>(cb, gate_w, gate_b, gating);
        moe_gemm_slow<<<dim3(ODIM / 128, BATCH / 128, NEXP), 256, 0, stream>>>(cb, expert_w, gating, expert_b, out);
    }
}

// Round 7
// 399.978 us; speedup vs baseline: 1.0944x; 1.0944x over previous
//
#include <hip/hip_runtime.h>
#include <hip/hip_bf16.h>

// Problem constants
#define BATCH   1024
#define FDIM    2048
#define LDIM    80
#define EDIM    512
#define ODIM    2048
#define NEXP    8
#define INDIM   2560   // FDIM + EDIM

// GEMM geometry (8-phase 256^2 template)
#define BM      256
#define BN      256
#define BK      64
#define NKT     (INDIM / BK)   // 40 K-tiles

typedef __bf16 bf16x8 __attribute__((ext_vector_type(8)));
typedef float  f32x4  __attribute__((ext_vector_type(4)));

__device__ __forceinline__ unsigned int pack2(float lo, float hi) {
    __hip_bfloat162 h = __float22bfloat162_rn(make_float2(lo, hi));
    unsigned int u;
    __builtin_memcpy(&u, &h, 4);
    return u;
}
__device__ __forceinline__ float bf2f(unsigned short h) {
    return __uint_as_float((unsigned int)h << 16);
}
__device__ __forceinline__ void gload_lds16(const void* g, void* l) {
    __builtin_amdgcn_global_load_lds(
        (__attribute__((address_space(1))) void*)g,
        (__attribute__((address_space(3))) void*)l,
        16, 0, 0);
}

#define BAR()       __builtin_amdgcn_s_barrier()
#define SCHED_PIN() __builtin_amdgcn_sched_barrier(0)

// ---------------------------------------------------------------------------
// Kernel 0: W fp32 [e][k][o] -> Wb bf16 [e][o][k]  (unchanged, HBM-bound)
// ---------------------------------------------------------------------------
__global__ __launch_bounds__(256) void convert_w(
    const float* __restrict__ W, unsigned short* __restrict__ Wb)
{
    const int t  = threadIdx.x;
    const int o  = blockIdx.x * 256 + t;
    const int k0 = blockIdx.y * 32;
    const int e  = blockIdx.z;
    const float* src = W + (size_t)e * ((size_t)INDIM * ODIM) + (size_t)k0 * ODIM + o;
    unsigned int pk[16];
    #pragma unroll
    for (int j = 0; j < 16; ++j) {
        float a = src[(size_t)(2 * j) * ODIM];
        float b = src[(size_t)(2 * j + 1) * ODIM];
        pk[j] = pack2(a, b);
    }
    uint4* dst = (uint4*)(Wb + (size_t)e * ((size_t)ODIM * INDIM) + (size_t)o * INDIM + k0);
    dst[0] = make_uint4(pk[0],  pk[1],  pk[2],  pk[3]);
    dst[1] = make_uint4(pk[4],  pk[5],  pk[6],  pk[7]);
    dst[2] = make_uint4(pk[8],  pk[9],  pk[10], pk[11]);
    dst[3] = make_uint4(pk[12], pk[13], pk[14], pk[15]);
}

// ---------------------------------------------------------------------------
// Kernel 1: combined = [features | labels @ label_embed] as bf16 (unchanged)
// ---------------------------------------------------------------------------
__global__ __launch_bounds__(256) void prep_kernel(
    const float* __restrict__ features, const float* __restrict__ labels,
    const float* __restrict__ label_embed, unsigned short* __restrict__ cb)
{
    const int b0 = blockIdx.x * 4;
    const int t  = threadIdx.x;
    __shared__ float lab[4][LDIM];
    for (int idx = t; idx < 4 * LDIM; idx += 256) {
        lab[idx / LDIM][idx % LDIM] = labels[(size_t)(b0 + idx / LDIM) * LDIM + (idx % LDIM)];
    }
    __syncthreads();

    {
        const int r = t >> 6, c64 = t & 63;
        const float4* F4 = (const float4*)features;
        #pragma unroll
        for (int ch = 0; ch < 8; ++ch) {
            float4 v = F4[(size_t)(b0 + r) * (FDIM / 4) + c64 + 64 * ch];
            uint2 pk;
            pk.x = pack2(v.x, v.y);
            pk.y = pack2(v.z, v.w);
            *(uint2*)(cb + (size_t)(b0 + r) * INDIM + (size_t)(c64 + 64 * ch) * 4) = pk;
        }
    }
    {
        const int j = 2 * t;
        float acc[4][2] = {{0,0},{0,0},{0,0},{0,0}};
        const float2* le2 = (const float2*)label_embed;
        for (int l = 0; l < LDIM; ++l) {
            float2 le = le2[(size_t)l * (EDIM / 2) + t];
            #pragma unroll
            for (int r = 0; r < 4; ++r) {
                float lv = lab[r][l];
                acc[r][0] += lv * le.x;
                acc[r][1] += lv * le.y;
            }
        }
        #pragma unroll
        for (int r = 0; r < 4; ++r) {
            *(unsigned int*)(cb + (size_t)(b0 + r) * INDIM + FDIM + j) = pack2(acc[r][0], acc[r][1]);
        }
    }
}

// ---------------------------------------------------------------------------
// Kernel 2: gating = sigmoid(combined @ gate_w + gate_b)  (unchanged)
// ---------------------------------------------------------------------------
__global__ __launch_bounds__(256) void gate_kernel(
    const unsigned short* __restrict__ cb, const float* __restrict__ gw,
    const float* __restrict__ gb, float* __restrict__ gating)
{
    const int b = blockIdx.x, t = threadIdx.x;
    float p[NEXP] = {0,0,0,0,0,0,0,0};
    for (int i = t; i < INDIM; i += 256) {
        float c = bf2f(cb[(size_t)b * INDIM + i]);
        const float4* g4 = (const float4*)(gw + (size_t)i * NEXP);
        float4 u = g4[0], v = g4[1];
        p[0] += c * u.x; p[1] += c * u.y; p[2] += c * u.z; p[3] += c * u.w;
        p[4] += c * v.x; p[5] += c * v.y; p[6] += c * v.z; p[7] += c * v.w;
    }
    __shared__ float red[4][NEXP];
    const int lane = t & 63, wave = t >> 6;
    #pragma unroll
    for (int e = 0; e < NEXP; ++e) {
        float v = p[e];
        v += __shfl_down(v, 32); v += __shfl_down(v, 16); v += __shfl_down(v, 8);
        v += __shfl_down(v, 4);  v += __shfl_down(v, 2);  v += __shfl_down(v, 1);
        if (lane == 0) red[wave][e] = v;
    }
    __syncthreads();
    if (t < NEXP) {
        float s = red[0][t] + red[1][t] + red[2][t] + red[3][t] + gb[t];
        gating[(size_t)b * NEXP + t] = 1.0f / (1.0f + __expf(-s));
    }
}

// ---------------------------------------------------------------------------
// Kernel 3 (fast path): 256x256 8-phase pipelined MFMA GEMM.
// K-loop identical to round 6 (named As0/Bs0/As1/Bs1, counted vmcnt(4)).
// EPILOGUE is now templated:
//   ATOMIC=true : gated+biased atomicAdd into out  (old behavior, fallback)
//   ATOMIC=false: gated+biased PLAIN STORES into parts[e][m][n]; a separate
//                 combine kernel sums over e. Removes 16.7M cross-XCD
//                 device-scope fp32 RMWs (WRITE_SIZE showed 64 MB = 8x output
//                 written through HBM) — the schedule-insensitive stall suspect.
// ---------------------------------------------------------------------------
template<bool ATOMIC>
__global__ __launch_bounds__(512, 2) void moe_gemm8(
    const unsigned short* __restrict__ cb, const unsigned short* __restrict__ Wb,
    const float* __restrict__ gating, const float* __restrict__ eb,
    float* __restrict__ dst)
{
    __shared__ unsigned short As0[256 * 64];   // 32 KiB each, 128 KiB total
    __shared__ unsigned short Bs0[256 * 64];
    __shared__ unsigned short As1[256 * 64];
    __shared__ unsigned short Bs1[256 * 64];

    const int t = threadIdx.x;
    const int lane = t & 63, wave = t >> 6;
    const int n0 = blockIdx.x * BN;
    const int m0 = blockIdx.y * BM;
    const int e  = blockIdx.z;

    const int wmi = wave >> 2;            // 0..1
    const int wni = wave & 3;             // 0..3
    const int wmBase = wmi * 128;
    const int wnBase = wni * 64;
    const int fm = lane & 15, fq = lane >> 4;
    const int fsw = fm & 7;               // row&7 for all fragment rows

    // staging source: thread t covers LDS row srow, physical chunk t&7;
    // pre-swizzle the GLOBAL chunk so LDS[row][pc] = global[row][pc ^ (row&7)]
    const int srow = t >> 3;                        // 0..63
    const int scn  = (t & 7) ^ (srow & 7);
    const size_t gOff = (size_t)srow * INDIM + (size_t)scn * 8;
    const unsigned short* aS = cb + (size_t)m0 * INDIM + gOff;
    const unsigned short* bS = Wb + (size_t)e * ((size_t)ODIM * INDIM)
                                  + (size_t)n0 * INDIM + gOff;

    #define STAGE4_A(DST, kt) { _Pragma("unroll") for (int q = 0; q < 4; ++q) \
        gload_lds16(aS + (size_t)q * (64 * INDIM) + (size_t)(kt) * 64, (DST) + q * 4096 + wave * 512); }
    #define STAGE4_B(DST, kt) { _Pragma("unroll") for (int q = 0; q < 4; ++q) \
        gload_lds16(bS + (size_t)q * (64 * INDIM) + (size_t)(kt) * 64, (DST) + q * 4096 + wave * 512); }

    #define PH_READ_A(RA, base) { _Pragma("unroll") for (int mi = 0; mi < 4; ++mi) \
        _Pragma("unroll") for (int ks = 0; ks < 2; ++ks) \
            af[mi][ks] = *(const bf16x8*)((RA) + (wmBase + (base) + mi * 16 + fm) * 64 \
                                               + (((ks * 4 + fq) ^ fsw) * 8)); }
    #define PH_READ_B(BF, RB, base) { _Pragma("unroll") for (int ni = 0; ni < 2; ++ni) \
        _Pragma("unroll") for (int ks = 0; ks < 2; ++ks) \
            BF[ni][ks] = *(const bf16x8*)((RB) + (wnBase + (base) + ni * 16 + fm) * 64 \
                                               + (((ks * 4 + fq) ^ fsw) * 8)); }
    #define MFMA16(AI, AJ, BF) { __builtin_amdgcn_s_setprio(1); \
        _Pragma("unroll") for (int mi = 0; mi < 4; ++mi) \
        _Pragma("unroll") for (int ni = 0; ni < 2; ++ni) \
        _Pragma("unroll") for (int ks = 0; ks < 2; ++ks) \
            acc[(AI) + mi][(AJ) + ni] = __builtin_amdgcn_mfma_f32_16x16x32_bf16( \
                af[mi][ks], BF[ni][ks], acc[(AI) + mi][(AJ) + ni], 0, 0, 0); \
        __builtin_amdgcn_s_setprio(0); }

    f32x4 acc[8][4];
    #pragma unroll
    for (int i = 0; i < 8; ++i)
        #pragma unroll
        for (int j = 0; j < 4; ++j) acc[i][j] = (f32x4){0.f, 0.f, 0.f, 0.f};

    bf16x8 af[4][2], bA[2][2], bB[2][2];

    // Prologue: T0 fully -> As0/Bs0 (8), T1's B -> Bs1 (4).
    STAGE4_A(As0, 0); STAGE4_B(Bs0, 0); STAGE4_B(Bs1, 1);
    asm volatile("s_waitcnt vmcnt(4)");   // T0 resident; T1-B stays in flight
    BAR(); SCHED_PIN();

    #define TILE(kt, RA, RB, OA) { \
        /* phase 1: C(mh0,nh0) */ \
        PH_READ_A(RA, 0); \
        PH_READ_B(bA, RB, 0); \
        if ((kt) + 1 < NKT) STAGE4_A(OA, (kt) + 1); \
        BAR(); \
        MFMA16(0, 0, bA); \
        SCHED_PIN(); BAR(); SCHED_PIN(); \
        /* phase 2: C(mh0,nh1) */ \
        PH_READ_B(bB, RB, 32); \
        BAR(); \
        MFMA16(0, 2, bB); \
        SCHED_PIN(); BAR(); SCHED_PIN(); \
        /* phase 3: C(mh1,nh1) */ \
        PH_READ_A(RA, 64); \
        BAR(); \
        MFMA16(4, 2, bB); \
        SCHED_PIN(); BAR(); SCHED_PIN(); \
        /* phase 4: C(mh1,nh0); stage next-next B into cur-B (reads done ph2) */ \
        if ((kt) + 2 < NKT) STAGE4_B(RB, (kt) + 2); \
        BAR(); \
        MFMA16(4, 0, bA); \
        SCHED_PIN(); \
        if ((kt) + 2 < NKT) { asm volatile("s_waitcnt vmcnt(4)"); } \
        else                { asm volatile("s_waitcnt vmcnt(0)"); } \
        BAR(); SCHED_PIN(); \
    }

    for (int kt = 0; kt < NKT; kt += 2) {
        TILE(kt,     As0, Bs0, As1);
        TILE(kt + 1, As1, Bs1, As0);
    }
    #undef TILE
    #undef STAGE4_A
    #undef STAGE4_B
    #undef PH_READ_A
    #undef PH_READ_B
    #undef MFMA16

    // Epilogue: gate-scale + gated bias.
    #pragma unroll
    for (int mi = 0; mi < 8; ++mi) {
        const int grow = m0 + wmBase + mi * 16 + fq * 4;
        const float g0 = gating[(size_t)(grow + 0) * NEXP + e];
        const float g1 = gating[(size_t)(grow + 1) * NEXP + e];
        const float g2 = gating[(size_t)(grow + 2) * NEXP + e];
        const float g3 = gating[(size_t)(grow + 3) * NEXP + e];
        #pragma unroll
        for (int ni = 0; ni < 4; ++ni) {
            const int gcol = n0 + wnBase + ni * 16 + fm;
            const float bias = eb[(size_t)e * ODIM + gcol];
            f32x4 a = acc[mi][ni];
            if (ATOMIC) {
                unsafeAtomicAdd(dst + (size_t)(grow + 0) * ODIM + gcol, g0 * (a.x + bias));
                unsafeAtomicAdd(dst + (size_t)(grow + 1) * ODIM + gcol, g1 * (a.y + bias));
                unsafeAtomicAdd(dst + (size_t)(grow + 2) * ODIM + gcol, g2 * (a.z + bias));
                unsafeAtomicAdd(dst + (size_t)(grow + 3) * ODIM + gcol, g3 * (a.w + bias));
            } else {
                float* pd = dst + ((size_t)e * BATCH + grow) * ODIM + gcol;
                pd[0 * ODIM] = g0 * (a.x + bias);
                pd[1 * ODIM] = g1 * (a.y + bias);
                pd[2 * ODIM] = g2 * (a.z + bias);
                pd[3 * ODIM] = g3 * (a.w + bias);
            }
        }
    }
}

// ---------------------------------------------------------------------------
// Kernel 4: out[m][n] = sum_e parts[e][m][n]. Streaming, float4, ~72 MB.
// ---------------------------------------------------------------------------
__global__ __launch_bounds__(256) void combine_kernel(
    const float* __restrict__ parts, float* __restrict__ out)
{
    const int idx = blockIdx.x * 256 + threadIdx.x;    // one float4 per thread
    const float4* p = (const float4*)parts;
    float4 s = p[idx];
    #pragma unroll
    for (int e = 1; e < NEXP; ++e) {
        float4 v = p[(size_t)e * (BATCH * ODIM / 4) + idx];
        s.x += v.x; s.y += v.y; s.z += v.z; s.w += v.w;
    }
    ((float4*)out)[idx] = s;
}

// ---------------------------------------------------------------------------
// Kernel 3 (fallback, small-ws): in-loop fp32->bf16 W staging (unchanged)
// ---------------------------------------------------------------------------
__global__ __launch_bounds__(256) void moe_gemm_slow(
    const unsigned short* __restrict__ cb, const float* __restrict__ W,
    const float* __restrict__ gating, const float* __restrict__ eb,
    float* __restrict__ out)
{
    __shared__ unsigned short As[128 * 32];
    __shared__ unsigned short Bs[128 * 32];

    const int t = threadIdx.x;
    const int lane = t & 63, wave = t >> 6;
    const int n0 = blockIdx.x * 128;
    const int m0 = blockIdx.y * 128;
    const int e  = blockIdx.z;

    f32x4 acc[4][4];
    #pragma unroll
    for (int i = 0; i < 4; ++i)
        #pragma unroll
        for (int j = 0; j < 4; ++j) acc[i][j] = (f32x4){0.f, 0.f, 0.f, 0.f};

    const int arow = t >> 2, acg = t & 3;
    const unsigned short* ag0 = cb + (size_t)(m0 + arow) * INDIM + acg * 8;
    unsigned short* al0 = As + wave * 512;
    unsigned short* al1 = As + 2048 + wave * 512;

    const int bg = t & 15;
    const int bu = t >> 4;
    const float* wg = W + (size_t)e * ((size_t)INDIM * ODIM) + (size_t)(2 * bg) * ODIM + n0 + bu * 8;
    unsigned int* bl = (unsigned int*)Bs + bg + bu * 128;

    const int fm = lane & 15, fq = lane >> 4;
    const int wn = (wave & 1) * 64;
    const int wm = (wave >> 1) * 64;

    for (int k0 = 0; k0 < INDIM; k0 += 32) {
        __syncthreads();
        gload_lds16(ag0 + k0, al0);
        gload_lds16(ag0 + (size_t)64 * INDIM + k0, al1);
        const float* wp = wg + (size_t)k0 * ODIM;
        float4 r0a = *(const float4*)(wp);
        float4 r0b = *(const float4*)(wp + 4);
        float4 r1a = *(const float4*)(wp + ODIM);
        float4 r1b = *(const float4*)(wp + ODIM + 4);
        bl[0 * 16] = pack2(r0a.x, r1a.x);
        bl[1 * 16] = pack2(r0a.y, r1a.y);
        bl[2 * 16] = pack2(r0a.z, r1a.z);
        bl[3 * 16] = pack2(r0a.w, r1a.w);
        bl[4 * 16] = pack2(r0b.x, r1b.x);
        bl[5 * 16] = pack2(r0b.y, r1b.y);
        bl[6 * 16] = pack2(r0b.z, r1b.z);
        bl[7 * 16] = pack2(r0b.w, r1b.w);
        __syncthreads();

        bf16x8 af[4], bfr[4];
        #pragma unroll
        for (int mi = 0; mi < 4; ++mi)
            af[mi] = *(const bf16x8*)(As + (wm + mi * 16 + fm) * 32 + fq * 8);
        #pragma unroll
        for (int ni = 0; ni < 4; ++ni)
            bfr[ni] = *(const bf16x8*)(Bs + (wn + ni * 16 + fm) * 32 + fq * 8);
        #pragma unroll
        for (int mi = 0; mi < 4; ++mi)
            #pragma unroll
            for (int ni = 0; ni < 4; ++ni)
                acc[mi][ni] = __builtin_amdgcn_mfma_f32_16x16x32_bf16(af[mi], bfr[ni], acc[mi][ni], 0, 0, 0);
    }

    #pragma unroll
    for (int mi = 0; mi < 4; ++mi) {
        const int grow = m0 + wm + mi * 16 + fq * 4;
        const float g0 = gating[(size_t)(grow + 0) * NEXP + e];
        const float g1 = gating[(size_t)(grow + 1) * NEXP + e];
        const float g2 = gating[(size_t)(grow + 2) * NEXP + e];
        const float g3 = gating[(size_t)(grow + 3) * NEXP + e];
        #pragma unroll
        for (int ni = 0; ni < 4; ++ni) {
            const int gcol = n0 + wn + ni * 16 + fm;
            const float bias = eb[(size_t)e * ODIM + gcol];
            f32x4 a = acc[mi][ni];
            unsafeAtomicAdd(out + (size_t)(grow + 0) * ODIM + gcol, g0 * (a.x + bias));
            unsafeAtomicAdd(out + (size_t)(grow + 1) * ODIM + gcol, g1 * (a.y + bias));
            unsafeAtomicAdd(out + (size_t)(grow + 2) * ODIM + gcol, g2 * (a.z + bias));
            unsafeAtomicAdd(out + (size_t)(grow + 3) * ODIM + gcol, g3 * (a.w + bias));
        }
    }
}

// ---------------------------------------------------------------------------
extern "C" void kernel_launch(void* const* d_in, const int* in_sizes, int n_in,
                              void* d_out, int out_size, void* d_ws, size_t ws_size,
                              hipStream_t stream) {
    const float* features    = (const float*)d_in[0];
    const float* labels      = (const float*)d_in[1];
    const float* label_embed = (const float*)d_in[2];
    const float* gate_w      = (const float*)d_in[3];
    const float* gate_b      = (const float*)d_in[4];
    const float* expert_w    = (const float*)d_in[5];
    const float* expert_b    = (const float*)d_in[6];
    float* out = (float*)d_out;

    // ws layout: Wb bf16 [8][2048][2560] | cb bf16 [1024][2560] | gating f32 |
    //            parts f32 [8][1024][2048]  (parts only on the fast2 path)
    const size_t wb_bytes = (size_t)NEXP * ODIM * INDIM * 2;        // 83,886,080
    const size_t cb_bytes = (size_t)BATCH * INDIM * 2;              //  5,242,880
    const size_t gt_bytes = (size_t)BATCH * NEXP * 4;               //     32,768
    const size_t pt_bytes = (size_t)NEXP * BATCH * ODIM * 4;        // 67,108,864
    const bool fast  = ws_size >= wb_bytes + cb_bytes + gt_bytes;
    const bool fast2 = ws_size >= wb_bytes + cb_bytes + gt_bytes + pt_bytes;

    if (fast) {
        unsigned short* Wb = (unsigned short*)d_ws;
        unsigned short* cb = (unsigned short*)((char*)d_ws + wb_bytes);
        float* gating = (float*)((char*)d_ws + wb_bytes + cb_bytes);
        float* parts  = (float*)((char*)d_ws + wb_bytes + cb_bytes + gt_bytes);
        convert_w<<<dim3(ODIM / 256, INDIM / 32, NEXP), 256, 0, stream>>>(expert_w, Wb);
        prep_kernel<<<BATCH / 4, 256, 0, stream>>>(features, labels, label_embed, cb);
        gate_kernel<<<BATCH, 256, 0, stream>>>(cb, gate_w, gate_b, gating);
        if (fast2) {
            moe_gemm8<false><<<dim3(ODIM / BN, BATCH / BM, NEXP), 512, 0, stream>>>(cb, Wb, gating, expert_b, parts);
            combine_kernel<<<(BATCH * ODIM / 4) / 256, 256, 0, stream>>>(parts, out);
        } else {
            hipMemsetAsync(d_out, 0, (size_t)BATCH * ODIM * sizeof(float), stream);
            moe_gemm8<true><<<dim3(ODIM / BN, BATCH / BM, NEXP), 512, 0, stream>>>(cb, Wb, gating, expert_b, out);
        }
    } else {
        unsigned short* cb = (unsigned short*)d_ws;
        float* gating = (float*)((char*)d_ws + cb_bytes);
        hipMemsetAsync(d_out, 0, (size_t)BATCH * ODIM * sizeof(float), stream);
        prep_kernel<<<BATCH / 4, 256, 0, stream>>>(features, labels, label_embed, cb);
        gate_kernel<<<BATCH, 256, 0, stream>>>(cb, gate_w, gate_b, gating);
        moe_gemm_slow<<<dim3(ODIM / 128, BATCH / 128, NEXP), 256, 0, stream>>>(cb, expert_w, gating, expert_b, out);
    }
}

// Round 8
// 377.271 us; speedup vs baseline: 1.1603x; 1.0602x over previous
//
#include <hip/hip_runtime.h>
#include <hip/hip_bf16.h>

// Problem constants
#define BATCH   1024
#define FDIM    2048
#define LDIM    80
#define EDIM    512
#define ODIM    2048
#define NEXP    8
#define INDIM   2560   // FDIM + EDIM

// GEMM geometry (8-phase 256^2 template)
#define BM      256
#define BN      256
#define BK      64
#define NKT     (INDIM / BK)   // 40 K-tiles

typedef __bf16 bf16x8 __attribute__((ext_vector_type(8)));
typedef float  f32x4  __attribute__((ext_vector_type(4)));

__device__ __forceinline__ unsigned int pack2(float lo, float hi) {
    __hip_bfloat162 h = __float22bfloat162_rn(make_float2(lo, hi));
    unsigned int u;
    __builtin_memcpy(&u, &h, 4);
    return u;
}
__device__ __forceinline__ float bf2f(unsigned short h) {
    return __uint_as_float((unsigned int)h << 16);
}
__device__ __forceinline__ void gload_lds16(const void* g, void* l) {
    __builtin_amdgcn_global_load_lds(
        (__attribute__((address_space(1))) void*)g,
        (__attribute__((address_space(3))) void*)l,
        16, 0, 0);
}

#define BAR()       __builtin_amdgcn_s_barrier()
#define SCHED_PIN() __builtin_amdgcn_sched_barrier(0)

// ---------------------------------------------------------------------------
// Kernel 0 v2: W fp32 [e][k][o] -> Wb bf16 [e][o][k], LDS tile transpose.
// Old version wrote 64B chunks at 5120B stride -> partial-128B-line stores ->
// L2 read-for-ownership (FETCH_SIZE ~= output size despite L3-resident input)
// serialized into the write path (105us, 2.4 TB/s). Now: 128k x 64o tiles;
// coalesced float4 reads -> LDS [128][68] f32 (pad 4 => 16B-aligned b128
// ds_writes; transposed read 4-way conflict is off critical path) -> each
// output row written as 256B contiguous (4 lanes x uint4). Full-line writes,
// no RFO.
// ---------------------------------------------------------------------------
#define CW_TK 128   // k rows per tile
#define CW_TO 64    // o cols per tile
__global__ __launch_bounds__(256) void convert_w(
    const float* __restrict__ W, unsigned short* __restrict__ Wb)
{
    __shared__ float tile[CW_TK][CW_TO + 4];   // 128 x 68 x 4B = 34 KiB

    const int t  = threadIdx.x;
    const int o0 = blockIdx.x * CW_TO;
    const int k0 = blockIdx.y * CW_TK;
    const int e  = blockIdx.z;

    // Read: 128 rows x 256B; wave reads 4 rows x (16 lanes x float4).
    const int rl = t & 15;          // 16B chunk within row
    const int rr = t >> 4;          // row 0..15 (+16 per pass)
    const float* src = W + (size_t)e * ((size_t)INDIM * ODIM)
                         + (size_t)(k0 + rr) * ODIM + o0 + rl * 4;
    #pragma unroll
    for (int p = 0; p < CW_TK / 16; ++p) {
        float4 v = *(const float4*)(src + (size_t)(p * 16) * ODIM);
        *(float4*)&tile[rr + p * 16][rl * 4] = v;
    }
    __syncthreads();

    // Write: 64 o-rows x 256B contiguous. thread: o = t>>2, 64B chunk c = t&3.
    const int o = t >> 2;
    const int c = t & 3;
    unsigned short* dst = Wb + (size_t)e * ((size_t)ODIM * INDIM)
                             + (size_t)(o0 + o) * INDIM + k0 + c * 32;
    #pragma unroll
    for (int u = 0; u < 4; ++u) {
        const int kb = c * 32 + u * 8;
        unsigned int w0 = pack2(tile[kb + 0][o], tile[kb + 1][o]);
        unsigned int w1 = pack2(tile[kb + 2][o], tile[kb + 3][o]);
        unsigned int w2 = pack2(tile[kb + 4][o], tile[kb + 5][o]);
        unsigned int w3 = pack2(tile[kb + 6][o], tile[kb + 7][o]);
        ((uint4*)dst)[u] = make_uint4(w0, w1, w2, w3);
    }
}

// ---------------------------------------------------------------------------
// Kernel 1: combined = [features | labels @ label_embed] as bf16 (unchanged)
// ---------------------------------------------------------------------------
__global__ __launch_bounds__(256) void prep_kernel(
    const float* __restrict__ features, const float* __restrict__ labels,
    const float* __restrict__ label_embed, unsigned short* __restrict__ cb)
{
    const int b0 = blockIdx.x * 4;
    const int t  = threadIdx.x;
    __shared__ float lab[4][LDIM];
    for (int idx = t; idx < 4 * LDIM; idx += 256) {
        lab[idx / LDIM][idx % LDIM] = labels[(size_t)(b0 + idx / LDIM) * LDIM + (idx % LDIM)];
    }
    __syncthreads();

    {
        const int r = t >> 6, c64 = t & 63;
        const float4* F4 = (const float4*)features;
        #pragma unroll
        for (int ch = 0; ch < 8; ++ch) {
            float4 v = F4[(size_t)(b0 + r) * (FDIM / 4) + c64 + 64 * ch];
            uint2 pk;
            pk.x = pack2(v.x, v.y);
            pk.y = pack2(v.z, v.w);
            *(uint2*)(cb + (size_t)(b0 + r) * INDIM + (size_t)(c64 + 64 * ch) * 4) = pk;
        }
    }
    {
        const int j = 2 * t;
        float acc[4][2] = {{0,0},{0,0},{0,0},{0,0}};
        const float2* le2 = (const float2*)label_embed;
        for (int l = 0; l < LDIM; ++l) {
            float2 le = le2[(size_t)l * (EDIM / 2) + t];
            #pragma unroll
            for (int r = 0; r < 4; ++r) {
                float lv = lab[r][l];
                acc[r][0] += lv * le.x;
                acc[r][1] += lv * le.y;
            }
        }
        #pragma unroll
        for (int r = 0; r < 4; ++r) {
            *(unsigned int*)(cb + (size_t)(b0 + r) * INDIM + FDIM + j) = pack2(acc[r][0], acc[r][1]);
        }
    }
}

// ---------------------------------------------------------------------------
// Kernel 2: gating = sigmoid(combined @ gate_w + gate_b)  (unchanged)
// ---------------------------------------------------------------------------
__global__ __launch_bounds__(256) void gate_kernel(
    const unsigned short* __restrict__ cb, const float* __restrict__ gw,
    const float* __restrict__ gb, float* __restrict__ gating)
{
    const int b = blockIdx.x, t = threadIdx.x;
    float p[NEXP] = {0,0,0,0,0,0,0,0};
    for (int i = t; i < INDIM; i += 256) {
        float c = bf2f(cb[(size_t)b * INDIM + i]);
        const float4* g4 = (const float4*)(gw + (size_t)i * NEXP);
        float4 u = g4[0], v = g4[1];
        p[0] += c * u.x; p[1] += c * u.y; p[2] += c * u.z; p[3] += c * u.w;
        p[4] += c * v.x; p[5] += c * v.y; p[6] += c * v.z; p[7] += c * v.w;
    }
    __shared__ float red[4][NEXP];
    const int lane = t & 63, wave = t >> 6;
    #pragma unroll
    for (int e = 0; e < NEXP; ++e) {
        float v = p[e];
        v += __shfl_down(v, 32); v += __shfl_down(v, 16); v += __shfl_down(v, 8);
        v += __shfl_down(v, 4);  v += __shfl_down(v, 2);  v += __shfl_down(v, 1);
        if (lane == 0) red[wave][e] = v;
    }
    __syncthreads();
    if (t < NEXP) {
        float s = red[0][t] + red[1][t] + red[2][t] + red[3][t] + gb[t];
        gating[(size_t)b * NEXP + t] = 1.0f / (1.0f + __expf(-s));
    }
}

// ---------------------------------------------------------------------------
// Kernel 3 (fast path): 256x256 8-phase pipelined MFMA GEMM.
// K-loop identical to round 6/7 (named As0/Bs0/As1/Bs1, counted vmcnt(4)).
// Epilogue templated: ATOMIC=false writes gated+biased partials (plain
// stores, no cross-XCD RMW — confirmed ~45us win in round 7).
// ---------------------------------------------------------------------------
template<bool ATOMIC>
__global__ __launch_bounds__(512, 2) void moe_gemm8(
    const unsigned short* __restrict__ cb, const unsigned short* __restrict__ Wb,
    const float* __restrict__ gating, const float* __restrict__ eb,
    float* __restrict__ dst)
{
    __shared__ unsigned short As0[256 * 64];   // 32 KiB each, 128 KiB total
    __shared__ unsigned short Bs0[256 * 64];
    __shared__ unsigned short As1[256 * 64];
    __shared__ unsigned short Bs1[256 * 64];

    const int t = threadIdx.x;
    const int lane = t & 63, wave = t >> 6;
    const int n0 = blockIdx.x * BN;
    const int m0 = blockIdx.y * BM;
    const int e  = blockIdx.z;

    const int wmi = wave >> 2;            // 0..1
    const int wni = wave & 3;             // 0..3
    const int wmBase = wmi * 128;
    const int wnBase = wni * 64;
    const int fm = lane & 15, fq = lane >> 4;
    const int fsw = fm & 7;               // row&7 for all fragment rows

    const int srow = t >> 3;                        // 0..63
    const int scn  = (t & 7) ^ (srow & 7);
    const size_t gOff = (size_t)srow * INDIM + (size_t)scn * 8;
    const unsigned short* aS = cb + (size_t)m0 * INDIM + gOff;
    const unsigned short* bS = Wb + (size_t)e * ((size_t)ODIM * INDIM)
                                  + (size_t)n0 * INDIM + gOff;

    #define STAGE4_A(DST, kt) { _Pragma("unroll") for (int q = 0; q < 4; ++q) \
        gload_lds16(aS + (size_t)q * (64 * INDIM) + (size_t)(kt) * 64, (DST) + q * 4096 + wave * 512); }
    #define STAGE4_B(DST, kt) { _Pragma("unroll") for (int q = 0; q < 4; ++q) \
        gload_lds16(bS + (size_t)q * (64 * INDIM) + (size_t)(kt) * 64, (DST) + q * 4096 + wave * 512); }

    #define PH_READ_A(RA, base) { _Pragma("unroll") for (int mi = 0; mi < 4; ++mi) \
        _Pragma("unroll") for (int ks = 0; ks < 2; ++ks) \
            af[mi][ks] = *(const bf16x8*)((RA) + (wmBase + (base) + mi * 16 + fm) * 64 \
                                               + (((ks * 4 + fq) ^ fsw) * 8)); }
    #define PH_READ_B(BF, RB, base) { _Pragma("unroll") for (int ni = 0; ni < 2; ++ni) \
        _Pragma("unroll") for (int ks = 0; ks < 2; ++ks) \
            BF[ni][ks] = *(const bf16x8*)((RB) + (wnBase + (base) + ni * 16 + fm) * 64 \
                                               + (((ks * 4 + fq) ^ fsw) * 8)); }
    #define MFMA16(AI, AJ, BF) { __builtin_amdgcn_s_setprio(1); \
        _Pragma("unroll") for (int mi = 0; mi < 4; ++mi) \
        _Pragma("unroll") for (int ni = 0; ni < 2; ++ni) \
        _Pragma("unroll") for (int ks = 0; ks < 2; ++ks) \
            acc[(AI) + mi][(AJ) + ni] = __builtin_amdgcn_mfma_f32_16x16x32_bf16( \
                af[mi][ks], BF[ni][ks], acc[(AI) + mi][(AJ) + ni], 0, 0, 0); \
        __builtin_amdgcn_s_setprio(0); }

    f32x4 acc[8][4];
    #pragma unroll
    for (int i = 0; i < 8; ++i)
        #pragma unroll
        for (int j = 0; j < 4; ++j) acc[i][j] = (f32x4){0.f, 0.f, 0.f, 0.f};

    bf16x8 af[4][2], bA[2][2], bB[2][2];

    // Prologue: T0 fully -> As0/Bs0 (8), T1's B -> Bs1 (4).
    STAGE4_A(As0, 0); STAGE4_B(Bs0, 0); STAGE4_B(Bs1, 1);
    asm volatile("s_waitcnt vmcnt(4)");   // T0 resident; T1-B stays in flight
    BAR(); SCHED_PIN();

    #define TILE(kt, RA, RB, OA) { \
        /* phase 1: C(mh0,nh0) */ \
        PH_READ_A(RA, 0); \
        PH_READ_B(bA, RB, 0); \
        if ((kt) + 1 < NKT) STAGE4_A(OA, (kt) + 1); \
        BAR(); \
        MFMA16(0, 0, bA); \
        SCHED_PIN(); BAR(); SCHED_PIN(); \
        /* phase 2: C(mh0,nh1) */ \
        PH_READ_B(bB, RB, 32); \
        BAR(); \
        MFMA16(0, 2, bB); \
        SCHED_PIN(); BAR(); SCHED_PIN(); \
        /* phase 3: C(mh1,nh1) */ \
        PH_READ_A(RA, 64); \
        BAR(); \
        MFMA16(4, 2, bB); \
        SCHED_PIN(); BAR(); SCHED_PIN(); \
        /* phase 4: C(mh1,nh0); stage next-next B into cur-B (reads done ph2) */ \
        if ((kt) + 2 < NKT) STAGE4_B(RB, (kt) + 2); \
        BAR(); \
        MFMA16(4, 0, bA); \
        SCHED_PIN(); \
        if ((kt) + 2 < NKT) { asm volatile("s_waitcnt vmcnt(4)"); } \
        else                { asm volatile("s_waitcnt vmcnt(0)"); } \
        BAR(); SCHED_PIN(); \
    }

    for (int kt = 0; kt < NKT; kt += 2) {
        TILE(kt,     As0, Bs0, As1);
        TILE(kt + 1, As1, Bs1, As0);
    }
    #undef TILE
    #undef STAGE4_A
    #undef STAGE4_B
    #undef PH_READ_A
    #undef PH_READ_B
    #undef MFMA16

    // Epilogue: gate-scale + gated bias.
    #pragma unroll
    for (int mi = 0; mi < 8; ++mi) {
        const int grow = m0 + wmBase + mi * 16 + fq * 4;
        const float g0 = gating[(size_t)(grow + 0) * NEXP + e];
        const float g1 = gating[(size_t)(grow + 1) * NEXP + e];
        const float g2 = gating[(size_t)(grow + 2) * NEXP + e];
        const float g3 = gating[(size_t)(grow + 3) * NEXP + e];
        #pragma unroll
        for (int ni = 0; ni < 4; ++ni) {
            const int gcol = n0 + wnBase + ni * 16 + fm;
            const float bias = eb[(size_t)e * ODIM + gcol];
            f32x4 a = acc[mi][ni];
            if (ATOMIC) {
                unsafeAtomicAdd(dst + (size_t)(grow + 0) * ODIM + gcol, g0 * (a.x + bias));
                unsafeAtomicAdd(dst + (size_t)(grow + 1) * ODIM + gcol, g1 * (a.y + bias));
                unsafeAtomicAdd(dst + (size_t)(grow + 2) * ODIM + gcol, g2 * (a.z + bias));
                unsafeAtomicAdd(dst + (size_t)(grow + 3) * ODIM + gcol, g3 * (a.w + bias));
            } else {
                float* pd = dst + ((size_t)e * BATCH + grow) * ODIM + gcol;
                pd[0 * ODIM] = g0 * (a.x + bias);
                pd[1 * ODIM] = g1 * (a.y + bias);
                pd[2 * ODIM] = g2 * (a.z + bias);
                pd[3 * ODIM] = g3 * (a.w + bias);
            }
        }
    }
}

// ---------------------------------------------------------------------------
// Kernel 4: out[m][n] = sum_e parts[e][m][n]. Streaming, float4, ~72 MB.
// ---------------------------------------------------------------------------
__global__ __launch_bounds__(256) void combine_kernel(
    const float* __restrict__ parts, float* __restrict__ out)
{
    const int idx = blockIdx.x * 256 + threadIdx.x;    // one float4 per thread
    const float4* p = (const float4*)parts;
    float4 s = p[idx];
    #pragma unroll
    for (int e = 1; e < NEXP; ++e) {
        float4 v = p[(size_t)e * (BATCH * ODIM / 4) + idx];
        s.x += v.x; s.y += v.y; s.z += v.z; s.w += v.w;
    }
    ((float4*)out)[idx] = s;
}

// ---------------------------------------------------------------------------
// Kernel 3 (fallback, small-ws): in-loop fp32->bf16 W staging (unchanged)
// ---------------------------------------------------------------------------
__global__ __launch_bounds__(256) void moe_gemm_slow(
    const unsigned short* __restrict__ cb, const float* __restrict__ W,
    const float* __restrict__ gating, const float* __restrict__ eb,
    float* __restrict__ out)
{
    __shared__ unsigned short As[128 * 32];
    __shared__ unsigned short Bs[128 * 32];

    const int t = threadIdx.x;
    const int lane = t & 63, wave = t >> 6;
    const int n0 = blockIdx.x * 128;
    const int m0 = blockIdx.y * 128;
    const int e  = blockIdx.z;

    f32x4 acc[4][4];
    #pragma unroll
    for (int i = 0; i < 4; ++i)
        #pragma unroll
        for (int j = 0; j < 4; ++j) acc[i][j] = (f32x4){0.f, 0.f, 0.f, 0.f};

    const int arow = t >> 2, acg = t & 3;
    const unsigned short* ag0 = cb + (size_t)(m0 + arow) * INDIM + acg * 8;
    unsigned short* al0 = As + wave * 512;
    unsigned short* al1 = As + 2048 + wave * 512;

    const int bg = t & 15;
    const int bu = t >> 4;
    const float* wg = W + (size_t)e * ((size_t)INDIM * ODIM) + (size_t)(2 * bg) * ODIM + n0 + bu * 8;
    unsigned int* bl = (unsigned int*)Bs + bg + bu * 128;

    const int fm = lane & 15, fq = lane >> 4;
    const int wn = (wave & 1) * 64;
    const int wm = (wave >> 1) * 64;

    for (int k0 = 0; k0 < INDIM; k0 += 32) {
        __syncthreads();
        gload_lds16(ag0 + k0, al0);
        gload_lds16(ag0 + (size_t)64 * INDIM + k0, al1);
        const float* wp = wg + (size_t)k0 * ODIM;
        float4 r0a = *(const float4*)(wp);
        float4 r0b = *(const float4*)(wp + 4);
        float4 r1a = *(const float4*)(wp + ODIM);
        float4 r1b = *(const float4*)(wp + ODIM + 4);
        bl[0 * 16] = pack2(r0a.x, r1a.x);
        bl[1 * 16] = pack2(r0a.y, r1a.y);
        bl[2 * 16] = pack2(r0a.z, r1a.z);
        bl[3 * 16] = pack2(r0a.w, r1a.w);
        bl[4 * 16] = pack2(r0b.x, r1b.x);
        bl[5 * 16] = pack2(r0b.y, r1b.y);
        bl[6 * 16] = pack2(r0b.z, r1b.z);
        bl[7 * 16] = pack2(r0b.w, r1b.w);
        __syncthreads();

        bf16x8 af[4], bfr[4];
        #pragma unroll
        for (int mi = 0; mi < 4; ++mi)
            af[mi] = *(const bf16x8*)(As + (wm + mi * 16 + fm) * 32 + fq * 8);
        #pragma unroll
        for (int ni = 0; ni < 4; ++ni)
            bfr[ni] = *(const bf16x8*)(Bs + (wn + ni * 16 + fm) * 32 + fq * 8);
        #pragma unroll
        for (int mi = 0; mi < 4; ++mi)
            #pragma unroll
            for (int ni = 0; ni < 4; ++ni)
                acc[mi][ni] = __builtin_amdgcn_mfma_f32_16x16x32_bf16(af[mi], bfr[ni], acc[mi][ni], 0, 0, 0);
    }

    #pragma unroll
    for (int mi = 0; mi < 4; ++mi) {
        const int grow = m0 + wm + mi * 16 + fq * 4;
        const float g0 = gating[(size_t)(grow + 0) * NEXP + e];
        const float g1 = gating[(size_t)(grow + 1) * NEXP + e];
        const float g2 = gating[(size_t)(grow + 2) * NEXP + e];
        const float g3 = gating[(size_t)(grow + 3) * NEXP + e];
        #pragma unroll
        for (int ni = 0; ni < 4; ++ni) {
            const int gcol = n0 + wn + ni * 16 + fm;
            const float bias = eb[(size_t)e * ODIM + gcol];
            f32x4 a = acc[mi][ni];
            unsafeAtomicAdd(out + (size_t)(grow + 0) * ODIM + gcol, g0 * (a.x + bias));
            unsafeAtomicAdd(out + (size_t)(grow + 1) * ODIM + gcol, g1 * (a.y + bias));
            unsafeAtomicAdd(out + (size_t)(grow + 2) * ODIM + gcol, g2 * (a.z + bias));
            unsafeAtomicAdd(out + (size_t)(grow + 3) * ODIM + gcol, g3 * (a.w + bias));
        }
    }
}

// ---------------------------------------------------------------------------
extern "C" void kernel_launch(void* const* d_in, const int* in_sizes, int n_in,
                              void* d_out, int out_size, void* d_ws, size_t ws_size,
                              hipStream_t stream) {
    const float* features    = (const float*)d_in[0];
    const float* labels      = (const float*)d_in[1];
    const float* label_embed = (const float*)d_in[2];
    const float* gate_w      = (const float*)d_in[3];
    const float* gate_b      = (const float*)d_in[4];
    const float* expert_w    = (const float*)d_in[5];
    const float* expert_b    = (const float*)d_in[6];
    float* out = (float*)d_out;

    // ws layout: Wb bf16 [8][2048][2560] | cb bf16 [1024][2560] | gating f32 |
    //            parts f32 [8][1024][2048]  (parts only on the fast2 path)
    const size_t wb_bytes = (size_t)NEXP * ODIM * INDIM * 2;        // 83,886,080
    const size_t cb_bytes = (size_t)BATCH * INDIM * 2;              //  5,242,880
    const size_t gt_bytes = (size_t)BATCH * NEXP * 4;               //     32,768
    const size_t pt_bytes = (size_t)NEXP * BATCH * ODIM * 4;        // 67,108,864
    const bool fast  = ws_size >= wb_bytes + cb_bytes + gt_bytes;
    const bool fast2 = ws_size >= wb_bytes + cb_bytes + gt_bytes + pt_bytes;

    if (fast) {
        unsigned short* Wb = (unsigned short*)d_ws;
        unsigned short* cb = (unsigned short*)((char*)d_ws + wb_bytes);
        float* gating = (float*)((char*)d_ws + wb_bytes + cb_bytes);
        float* parts  = (float*)((char*)d_ws + wb_bytes + cb_bytes + gt_bytes);
        convert_w<<<dim3(ODIM / CW_TO, INDIM / CW_TK, NEXP), 256, 0, stream>>>(expert_w, Wb);
        prep_kernel<<<BATCH / 4, 256, 0, stream>>>(features, labels, label_embed, cb);
        gate_kernel<<<BATCH, 256, 0, stream>>>(cb, gate_w, gate_b, gating);
        if (fast2) {
            moe_gemm8<false><<<dim3(ODIM / BN, BATCH / BM, NEXP), 512, 0, stream>>>(cb, Wb, gating, expert_b, parts);
            combine_kernel<<<(BATCH * ODIM / 4) / 256, 256, 0, stream>>>(parts, out);
        } else {
            hipMemsetAsync(d_out, 0, (size_t)BATCH * ODIM * sizeof(float), stream);
            moe_gemm8<true><<<dim3(ODIM / BN, BATCH / BM, NEXP), 512, 0, stream>>>(cb, Wb, gating, expert_b, out);
        }
    } else {
        unsigned short* cb = (unsigned short*)d_ws;
        float* gating = (float*)((char*)d_ws + cb_bytes);
        hipMemsetAsync(d_out, 0, (size_t)BATCH * ODIM * sizeof(float), stream);
        prep_kernel<<<BATCH / 4, 256, 0, stream>>>(features, labels, label_embed, cb);
        gate_kernel<<<BATCH, 256, 0, stream>>>(cb, gate_w, gate_b, gating);
        moe_gemm_slow<<<dim3(ODIM / 128, BATCH / 128, NEXP), 256, 0, stream>>>(cb, expert_w, gating, expert_b, out);
    }
}

// Round 9
// 372.120 us; speedup vs baseline: 1.1763x; 1.0138x over previous
//
#include <hip/hip_runtime.h>
#include <hip/hip_bf16.h>

// Problem constants
#define BATCH   1024
#define FDIM    2048
#define LDIM    80
#define EDIM    512
#define ODIM    2048
#define NEXP    8
#define INDIM   2560   // FDIM + EDIM

// GEMM geometry (8-phase 256^2 template)
#define BM      256
#define BN      256
#define BK      64
#define NKT     (INDIM / BK)   // 40 K-tiles

typedef __bf16 bf16x8 __attribute__((ext_vector_type(8)));
typedef float  f32x4  __attribute__((ext_vector_type(4)));

__device__ __forceinline__ unsigned int pack2(float lo, float hi) {
    __hip_bfloat162 h = __float22bfloat162_rn(make_float2(lo, hi));
    unsigned int u;
    __builtin_memcpy(&u, &h, 4);
    return u;
}
__device__ __forceinline__ float bf2f(unsigned short h) {
    return __uint_as_float((unsigned int)h << 16);
}
__device__ __forceinline__ void gload_lds16(const void* g, void* l) {
    __builtin_amdgcn_global_load_lds(
        (__attribute__((address_space(1))) void*)g,
        (__attribute__((address_space(3))) void*)l,
        16, 0, 0);
}

#define BAR()       __builtin_amdgcn_s_barrier()
#define SCHED_PIN() __builtin_amdgcn_sched_barrier(0)

// convert tile geometry
#define CW_TK 128   // k rows per tile
#define CW_TO 64    // o cols per tile
#define CW_BLOCKS  ((ODIM / CW_TO) * (INDIM / CW_TK) * NEXP)   // 32*20*8 = 5120
#define PREP_BLOCKS (BATCH / 4)                                 // 256
#define GATE_BLOCKS (BATCH)                                     // 1024
#define FRONT_BLOCKS (CW_BLOCKS + PREP_BLOCKS + GATE_BLOCKS)    // 6400

// ---------------------------------------------------------------------------
// Kernel F (fused front): convert_w + prep + gate in ONE launch, partitioned
// by blockIdx. All three roles are data-independent (gate computes from fp32
// inputs directly, NOT from cb, so there is no prep->gate dependency).
// Rationale: each was individually sub-launch-gap scale or HBM-bound with
// idle VALU (convert: VALUBusy 3.5%); fusing removes 2 launch gaps and runs
// prep/gate inside convert's HBM shadow.
// ---------------------------------------------------------------------------
__global__ __launch_bounds__(256) void front_kernel(
    const float* __restrict__ W, unsigned short* __restrict__ Wb,
    const float* __restrict__ features, const float* __restrict__ labels,
    const float* __restrict__ label_embed, unsigned short* __restrict__ cb,
    const float* __restrict__ gw, const float* __restrict__ gb,
    float* __restrict__ gating)
{
    __shared__ float smem[CW_TK][CW_TO + 4];   // 34 KiB, overlaid per role
    const int bid = blockIdx.x;
    const int t   = threadIdx.x;

    if (bid < CW_BLOCKS) {
        // ---------------- convert role: W fp32 [e][k][o] -> Wb bf16 [e][o][k]
        // LDS tile transpose; coalesced float4 reads, full-line 256B writes
        // (partial-line writes caused L2 RFO = the old 105us — fixed in R7).
        const int o0 = (bid & 31) * CW_TO;
        const int k0 = ((bid >> 5) % (INDIM / CW_TK)) * CW_TK;
        const int e  = bid / ((ODIM / CW_TO) * (INDIM / CW_TK));

        const int rl = t & 15;
        const int rr = t >> 4;
        const float* src = W + (size_t)e * ((size_t)INDIM * ODIM)
                             + (size_t)(k0 + rr) * ODIM + o0 + rl * 4;
        #pragma unroll
        for (int p = 0; p < CW_TK / 16; ++p) {
            float4 v = *(const float4*)(src + (size_t)(p * 16) * ODIM);
            *(float4*)&smem[rr + p * 16][rl * 4] = v;
        }
        __syncthreads();

        const int o = t >> 2;
        const int c = t & 3;
        unsigned short* dst = Wb + (size_t)e * ((size_t)ODIM * INDIM)
                                 + (size_t)(o0 + o) * INDIM + k0 + c * 32;
        #pragma unroll
        for (int u = 0; u < 4; ++u) {
            const int kb = c * 32 + u * 8;
            unsigned int w0 = pack2(smem[kb + 0][o], smem[kb + 1][o]);
            unsigned int w1 = pack2(smem[kb + 2][o], smem[kb + 3][o]);
            unsigned int w2 = pack2(smem[kb + 4][o], smem[kb + 5][o]);
            unsigned int w3 = pack2(smem[kb + 6][o], smem[kb + 7][o]);
            ((uint4*)dst)[u] = make_uint4(w0, w1, w2, w3);
        }
    } else if (bid < CW_BLOCKS + PREP_BLOCKS) {
        // ---------------- prep role: cb = [features | labels @ label_embed] bf16
        const int b0 = (bid - CW_BLOCKS) * 4;
        float (*lab)[LDIM] = (float(*)[LDIM])smem;
        for (int idx = t; idx < 4 * LDIM; idx += 256) {
            lab[idx / LDIM][idx % LDIM] = labels[(size_t)(b0 + idx / LDIM) * LDIM + (idx % LDIM)];
        }
        __syncthreads();
        {
            const int r = t >> 6, c64 = t & 63;
            const float4* F4 = (const float4*)features;
            #pragma unroll
            for (int ch = 0; ch < 8; ++ch) {
                float4 v = F4[(size_t)(b0 + r) * (FDIM / 4) + c64 + 64 * ch];
                uint2 pk;
                pk.x = pack2(v.x, v.y);
                pk.y = pack2(v.z, v.w);
                *(uint2*)(cb + (size_t)(b0 + r) * INDIM + (size_t)(c64 + 64 * ch) * 4) = pk;
            }
        }
        {
            const int j = 2 * t;
            float acc[4][2] = {{0,0},{0,0},{0,0},{0,0}};
            const float2* le2 = (const float2*)label_embed;
            for (int l = 0; l < LDIM; ++l) {
                float2 le = le2[(size_t)l * (EDIM / 2) + t];
                #pragma unroll
                for (int r = 0; r < 4; ++r) {
                    float lv = lab[r][l];
                    acc[r][0] += lv * le.x;
                    acc[r][1] += lv * le.y;
                }
            }
            #pragma unroll
            for (int r = 0; r < 4; ++r) {
                *(unsigned int*)(cb + (size_t)(b0 + r) * INDIM + FDIM + j) = pack2(acc[r][0], acc[r][1]);
            }
        }
    } else {
        // ---------------- gate role: gating = sigmoid([F | labels@E] @ gw + gb)
        // computed from fp32 inputs (independent of prep's cb)
        const int b = bid - CW_BLOCKS - PREP_BLOCKS;
        float* labs = (float*)smem;                       // [80]
        float (*red)[NEXP] = (float(*)[NEXP])((float*)smem + 128);
        if (t < LDIM) labs[t] = labels[(size_t)b * LDIM + t];
        __syncthreads();

        float p[NEXP] = {0,0,0,0,0,0,0,0};
        for (int i = t; i < FDIM; i += 256) {
            float c = features[(size_t)b * FDIM + i];
            const float4* g4 = (const float4*)(gw + (size_t)i * NEXP);
            float4 u = g4[0], v = g4[1];
            p[0] += c * u.x; p[1] += c * u.y; p[2] += c * u.z; p[3] += c * u.w;
            p[4] += c * v.x; p[5] += c * v.y; p[6] += c * v.z; p[7] += c * v.w;
        }
        // embed part: thread t owns columns j = t and j = t + 256
        float le0 = 0.f, le1 = 0.f;
        for (int l = 0; l < LDIM; ++l) {
            float lv = labs[l];
            le0 += lv * label_embed[(size_t)l * EDIM + t];
            le1 += lv * label_embed[(size_t)l * EDIM + t + 256];
        }
        {
            const float4* g4 = (const float4*)(gw + (size_t)(FDIM + t) * NEXP);
            float4 u = g4[0], v = g4[1];
            p[0] += le0 * u.x; p[1] += le0 * u.y; p[2] += le0 * u.z; p[3] += le0 * u.w;
            p[4] += le0 * v.x; p[5] += le0 * v.y; p[6] += le0 * v.z; p[7] += le0 * v.w;
            const float4* g5 = (const float4*)(gw + (size_t)(FDIM + 256 + t) * NEXP);
            float4 u2 = g5[0], v2 = g5[1];
            p[0] += le1 * u2.x; p[1] += le1 * u2.y; p[2] += le1 * u2.z; p[3] += le1 * u2.w;
            p[4] += le1 * v2.x; p[5] += le1 * v2.y; p[6] += le1 * v2.z; p[7] += le1 * v2.w;
        }
        const int lane = t & 63, wave = t >> 6;
        #pragma unroll
        for (int e = 0; e < NEXP; ++e) {
            float v = p[e];
            v += __shfl_down(v, 32); v += __shfl_down(v, 16); v += __shfl_down(v, 8);
            v += __shfl_down(v, 4);  v += __shfl_down(v, 2);  v += __shfl_down(v, 1);
            if (lane == 0) red[wave][e] = v;
        }
        __syncthreads();
        if (t < NEXP) {
            float s = red[0][t] + red[1][t] + red[2][t] + red[3][t] + gb[t];
            gating[(size_t)b * NEXP + t] = 1.0f / (1.0f + __expf(-s));
        }
    }
}

// ---------------------------------------------------------------------------
// Kernel 1/2 (retained for the small-ws fallback path only)
// ---------------------------------------------------------------------------
__global__ __launch_bounds__(256) void prep_kernel(
    const float* __restrict__ features, const float* __restrict__ labels,
    const float* __restrict__ label_embed, unsigned short* __restrict__ cb)
{
    const int b0 = blockIdx.x * 4;
    const int t  = threadIdx.x;
    __shared__ float lab[4][LDIM];
    for (int idx = t; idx < 4 * LDIM; idx += 256) {
        lab[idx / LDIM][idx % LDIM] = labels[(size_t)(b0 + idx / LDIM) * LDIM + (idx % LDIM)];
    }
    __syncthreads();

    {
        const int r = t >> 6, c64 = t & 63;
        const float4* F4 = (const float4*)features;
        #pragma unroll
        for (int ch = 0; ch < 8; ++ch) {
            float4 v = F4[(size_t)(b0 + r) * (FDIM / 4) + c64 + 64 * ch];
            uint2 pk;
            pk.x = pack2(v.x, v.y);
            pk.y = pack2(v.z, v.w);
            *(uint2*)(cb + (size_t)(b0 + r) * INDIM + (size_t)(c64 + 64 * ch) * 4) = pk;
        }
    }
    {
        const int j = 2 * t;
        float acc[4][2] = {{0,0},{0,0},{0,0},{0,0}};
        const float2* le2 = (const float2*)label_embed;
        for (int l = 0; l < LDIM; ++l) {
            float2 le = le2[(size_t)l * (EDIM / 2) + t];
            #pragma unroll
            for (int r = 0; r < 4; ++r) {
                float lv = lab[r][l];
                acc[r][0] += lv * le.x;
                acc[r][1] += lv * le.y;
            }
        }
        #pragma unroll
        for (int r = 0; r < 4; ++r) {
            *(unsigned int*)(cb + (size_t)(b0 + r) * INDIM + FDIM + j) = pack2(acc[r][0], acc[r][1]);
        }
    }
}

__global__ __launch_bounds__(256) void gate_kernel(
    const unsigned short* __restrict__ cb, const float* __restrict__ gw,
    const float* __restrict__ gb, float* __restrict__ gating)
{
    const int b = blockIdx.x, t = threadIdx.x;
    float p[NEXP] = {0,0,0,0,0,0,0,0};
    for (int i = t; i < INDIM; i += 256) {
        float c = bf2f(cb[(size_t)b * INDIM + i]);
        const float4* g4 = (const float4*)(gw + (size_t)i * NEXP);
        float4 u = g4[0], v = g4[1];
        p[0] += c * u.x; p[1] += c * u.y; p[2] += c * u.z; p[3] += c * u.w;
        p[4] += c * v.x; p[5] += c * v.y; p[6] += c * v.z; p[7] += c * v.w;
    }
    __shared__ float red[4][NEXP];
    const int lane = t & 63, wave = t >> 6;
    #pragma unroll
    for (int e = 0; e < NEXP; ++e) {
        float v = p[e];
        v += __shfl_down(v, 32); v += __shfl_down(v, 16); v += __shfl_down(v, 8);
        v += __shfl_down(v, 4);  v += __shfl_down(v, 2);  v += __shfl_down(v, 1);
        if (lane == 0) red[wave][e] = v;
    }
    __syncthreads();
    if (t < NEXP) {
        float s = red[0][t] + red[1][t] + red[2][t] + red[3][t] + gb[t];
        gating[(size_t)b * NEXP + t] = 1.0f / (1.0f + __expf(-s));
    }
}

// ---------------------------------------------------------------------------
// Kernel 3 (fast path): 256x256 8-phase pipelined MFMA GEMM (unchanged R6/R7
// K-loop; non-atomic epilogue writes gated+biased partials — R7-confirmed win).
// ---------------------------------------------------------------------------
template<bool ATOMIC>
__global__ __launch_bounds__(512, 2) void moe_gemm8(
    const unsigned short* __restrict__ cb, const unsigned short* __restrict__ Wb,
    const float* __restrict__ gating, const float* __restrict__ eb,
    float* __restrict__ dst)
{
    __shared__ unsigned short As0[256 * 64];   // 32 KiB each, 128 KiB total
    __shared__ unsigned short Bs0[256 * 64];
    __shared__ unsigned short As1[256 * 64];
    __shared__ unsigned short Bs1[256 * 64];

    const int t = threadIdx.x;
    const int lane = t & 63, wave = t >> 6;
    const int n0 = blockIdx.x * BN;
    const int m0 = blockIdx.y * BM;
    const int e  = blockIdx.z;

    const int wmi = wave >> 2;            // 0..1
    const int wni = wave & 3;             // 0..3
    const int wmBase = wmi * 128;
    const int wnBase = wni * 64;
    const int fm = lane & 15, fq = lane >> 4;
    const int fsw = fm & 7;               // row&7 for all fragment rows

    const int srow = t >> 3;                        // 0..63
    const int scn  = (t & 7) ^ (srow & 7);
    const size_t gOff = (size_t)srow * INDIM + (size_t)scn * 8;
    const unsigned short* aS = cb + (size_t)m0 * INDIM + gOff;
    const unsigned short* bS = Wb + (size_t)e * ((size_t)ODIM * INDIM)
                                  + (size_t)n0 * INDIM + gOff;

    #define STAGE4_A(DST, kt) { _Pragma("unroll") for (int q = 0; q < 4; ++q) \
        gload_lds16(aS + (size_t)q * (64 * INDIM) + (size_t)(kt) * 64, (DST) + q * 4096 + wave * 512); }
    #define STAGE4_B(DST, kt) { _Pragma("unroll") for (int q = 0; q < 4; ++q) \
        gload_lds16(bS + (size_t)q * (64 * INDIM) + (size_t)(kt) * 64, (DST) + q * 4096 + wave * 512); }

    #define PH_READ_A(RA, base) { _Pragma("unroll") for (int mi = 0; mi < 4; ++mi) \
        _Pragma("unroll") for (int ks = 0; ks < 2; ++ks) \
            af[mi][ks] = *(const bf16x8*)((RA) + (wmBase + (base) + mi * 16 + fm) * 64 \
                                               + (((ks * 4 + fq) ^ fsw) * 8)); }
    #define PH_READ_B(BF, RB, base) { _Pragma("unroll") for (int ni = 0; ni < 2; ++ni) \
        _Pragma("unroll") for (int ks = 0; ks < 2; ++ks) \
            BF[ni][ks] = *(const bf16x8*)((RB) + (wnBase + (base) + ni * 16 + fm) * 64 \
                                               + (((ks * 4 + fq) ^ fsw) * 8)); }
    #define MFMA16(AI, AJ, BF) { __builtin_amdgcn_s_setprio(1); \
        _Pragma("unroll") for (int mi = 0; mi < 4; ++mi) \
        _Pragma("unroll") for (int ni = 0; ni < 2; ++ni) \
        _Pragma("unroll") for (int ks = 0; ks < 2; ++ks) \
            acc[(AI) + mi][(AJ) + ni] = __builtin_amdgcn_mfma_f32_16x16x32_bf16( \
                af[mi][ks], BF[ni][ks], acc[(AI) + mi][(AJ) + ni], 0, 0, 0); \
        __builtin_amdgcn_s_setprio(0); }

    f32x4 acc[8][4];
    #pragma unroll
    for (int i = 0; i < 8; ++i)
        #pragma unroll
        for (int j = 0; j < 4; ++j) acc[i][j] = (f32x4){0.f, 0.f, 0.f, 0.f};

    bf16x8 af[4][2], bA[2][2], bB[2][2];

    // Prologue: T0 fully -> As0/Bs0 (8), T1's B -> Bs1 (4).
    STAGE4_A(As0, 0); STAGE4_B(Bs0, 0); STAGE4_B(Bs1, 1);
    asm volatile("s_waitcnt vmcnt(4)");   // T0 resident; T1-B stays in flight
    BAR(); SCHED_PIN();

    #define TILE(kt, RA, RB, OA) { \
        /* phase 1: C(mh0,nh0) */ \
        PH_READ_A(RA, 0); \
        PH_READ_B(bA, RB, 0); \
        if ((kt) + 1 < NKT) STAGE4_A(OA, (kt) + 1); \
        BAR(); \
        MFMA16(0, 0, bA); \
        SCHED_PIN(); BAR(); SCHED_PIN(); \
        /* phase 2: C(mh0,nh1) */ \
        PH_READ_B(bB, RB, 32); \
        BAR(); \
        MFMA16(0, 2, bB); \
        SCHED_PIN(); BAR(); SCHED_PIN(); \
        /* phase 3: C(mh1,nh1) */ \
        PH_READ_A(RA, 64); \
        BAR(); \
        MFMA16(4, 2, bB); \
        SCHED_PIN(); BAR(); SCHED_PIN(); \
        /* phase 4: C(mh1,nh0); stage next-next B into cur-B (reads done ph2) */ \
        if ((kt) + 2 < NKT) STAGE4_B(RB, (kt) + 2); \
        BAR(); \
        MFMA16(4, 0, bA); \
        SCHED_PIN(); \
        if ((kt) + 2 < NKT) { asm volatile("s_waitcnt vmcnt(4)"); } \
        else                { asm volatile("s_waitcnt vmcnt(0)"); } \
        BAR(); SCHED_PIN(); \
    }

    for (int kt = 0; kt < NKT; kt += 2) {
        TILE(kt,     As0, Bs0, As1);
        TILE(kt + 1, As1, Bs1, As0);
    }
    #undef TILE
    #undef STAGE4_A
    #undef STAGE4_B
    #undef PH_READ_A
    #undef PH_READ_B
    #undef MFMA16

    // Epilogue: gate-scale + gated bias.
    #pragma unroll
    for (int mi = 0; mi < 8; ++mi) {
        const int grow = m0 + wmBase + mi * 16 + fq * 4;
        const float g0 = gating[(size_t)(grow + 0) * NEXP + e];
        const float g1 = gating[(size_t)(grow + 1) * NEXP + e];
        const float g2 = gating[(size_t)(grow + 2) * NEXP + e];
        const float g3 = gating[(size_t)(grow + 3) * NEXP + e];
        #pragma unroll
        for (int ni = 0; ni < 4; ++ni) {
            const int gcol = n0 + wnBase + ni * 16 + fm;
            const float bias = eb[(size_t)e * ODIM + gcol];
            f32x4 a = acc[mi][ni];
            if (ATOMIC) {
                unsafeAtomicAdd(dst + (size_t)(grow + 0) * ODIM + gcol, g0 * (a.x + bias));
                unsafeAtomicAdd(dst + (size_t)(grow + 1) * ODIM + gcol, g1 * (a.y + bias));
                unsafeAtomicAdd(dst + (size_t)(grow + 2) * ODIM + gcol, g2 * (a.z + bias));
                unsafeAtomicAdd(dst + (size_t)(grow + 3) * ODIM + gcol, g3 * (a.w + bias));
            } else {
                float* pd = dst + ((size_t)e * BATCH + grow) * ODIM + gcol;
                pd[0 * ODIM] = g0 * (a.x + bias);
                pd[1 * ODIM] = g1 * (a.y + bias);
                pd[2 * ODIM] = g2 * (a.z + bias);
                pd[3 * ODIM] = g3 * (a.w + bias);
            }
        }
    }
}

// ---------------------------------------------------------------------------
// Kernel 4: out[m][n] = sum_e parts[e][m][n]. Streaming, float4, ~72 MB.
// ---------------------------------------------------------------------------
__global__ __launch_bounds__(256) void combine_kernel(
    const float* __restrict__ parts, float* __restrict__ out)
{
    const int idx = blockIdx.x * 256 + threadIdx.x;    // one float4 per thread
    const float4* p = (const float4*)parts;
    float4 s = p[idx];
    #pragma unroll
    for (int e = 1; e < NEXP; ++e) {
        float4 v = p[(size_t)e * (BATCH * ODIM / 4) + idx];
        s.x += v.x; s.y += v.y; s.z += v.z; s.w += v.w;
    }
    ((float4*)out)[idx] = s;
}

// ---------------------------------------------------------------------------
// Kernel 3 (fallback, small-ws): in-loop fp32->bf16 W staging (unchanged)
// ---------------------------------------------------------------------------
__global__ __launch_bounds__(256) void moe_gemm_slow(
    const unsigned short* __restrict__ cb, const float* __restrict__ W,
    const float* __restrict__ gating, const float* __restrict__ eb,
    float* __restrict__ out)
{
    __shared__ unsigned short As[128 * 32];
    __shared__ unsigned short Bs[128 * 32];

    const int t = threadIdx.x;
    const int lane = t & 63, wave = t >> 6;
    const int n0 = blockIdx.x * 128;
    const int m0 = blockIdx.y * 128;
    const int e  = blockIdx.z;

    f32x4 acc[4][4];
    #pragma unroll
    for (int i = 0; i < 4; ++i)
        #pragma unroll
        for (int j = 0; j < 4; ++j) acc[i][j] = (f32x4){0.f, 0.f, 0.f, 0.f};

    const int arow = t >> 2, acg = t & 3;
    const unsigned short* ag0 = cb + (size_t)(m0 + arow) * INDIM + acg * 8;
    unsigned short* al0 = As + wave * 512;
    unsigned short* al1 = As + 2048 + wave * 512;

    const int bg = t & 15;
    const int bu = t >> 4;
    const float* wg = W + (size_t)e * ((size_t)INDIM * ODIM) + (size_t)(2 * bg) * ODIM + n0 + bu * 8;
    unsigned int* bl = (unsigned int*)Bs + bg + bu * 128;

    const int fm = lane & 15, fq = lane >> 4;
    const int wn = (wave & 1) * 64;
    const int wm = (wave >> 1) * 64;

    for (int k0 = 0; k0 < INDIM; k0 += 32) {
        __syncthreads();
        gload_lds16(ag0 + k0, al0);
        gload_lds16(ag0 + (size_t)64 * INDIM + k0, al1);
        const float* wp = wg + (size_t)k0 * ODIM;
        float4 r0a = *(const float4*)(wp);
        float4 r0b = *(const float4*)(wp + 4);
        float4 r1a = *(const float4*)(wp + ODIM);
        float4 r1b = *(const float4*)(wp + ODIM + 4);
        bl[0 * 16] = pack2(r0a.x, r1a.x);
        bl[1 * 16] = pack2(r0a.y, r1a.y);
        bl[2 * 16] = pack2(r0a.z, r1a.z);
        bl[3 * 16] = pack2(r0a.w, r1a.w);
        bl[4 * 16] = pack2(r0b.x, r1b.x);
        bl[5 * 16] = pack2(r0b.y, r1b.y);
        bl[6 * 16] = pack2(r0b.z, r1b.z);
        bl[7 * 16] = pack2(r0b.w, r1b.w);
        __syncthreads();

        bf16x8 af[4], bfr[4];
        #pragma unroll
        for (int mi = 0; mi < 4; ++mi)
            af[mi] = *(const bf16x8*)(As + (wm + mi * 16 + fm) * 32 + fq * 8);
        #pragma unroll
        for (int ni = 0; ni < 4; ++ni)
            bfr[ni] = *(const bf16x8*)(Bs + (wn + ni * 16 + fm) * 32 + fq * 8);
        #pragma unroll
        for (int mi = 0; mi < 4; ++mi)
            #pragma unroll
            for (int ni = 0; ni < 4; ++ni)
                acc[mi][ni] = __builtin_amdgcn_mfma_f32_16x16x32_bf16(af[mi], bfr[ni], acc[mi][ni], 0, 0, 0);
    }

    #pragma unroll
    for (int mi = 0; mi < 4; ++mi) {
        const int grow = m0 + wm + mi * 16 + fq * 4;
        const float g0 = gating[(size_t)(grow + 0) * NEXP + e];
        const float g1 = gating[(size_t)(grow + 1) * NEXP + e];
        const float g2 = gating[(size_t)(grow + 2) * NEXP + e];
        const float g3 = gating[(size_t)(grow + 3) * NEXP + e];
        #pragma unroll
        for (int ni = 0; ni < 4; ++ni) {
            const int gcol = n0 + wn + ni * 16 + fm;
            const float bias = eb[(size_t)e * ODIM + gcol];
            f32x4 a = acc[mi][ni];
            unsafeAtomicAdd(out + (size_t)(grow + 0) * ODIM + gcol, g0 * (a.x + bias));
            unsafeAtomicAdd(out + (size_t)(grow + 1) * ODIM + gcol, g1 * (a.y + bias));
            unsafeAtomicAdd(out + (size_t)(grow + 2) * ODIM + gcol, g2 * (a.z + bias));
            unsafeAtomicAdd(out + (size_t)(grow + 3) * ODIM + gcol, g3 * (a.w + bias));
        }
    }
}

// ---------------------------------------------------------------------------
extern "C" void kernel_launch(void* const* d_in, const int* in_sizes, int n_in,
                              void* d_out, int out_size, void* d_ws, size_t ws_size,
                              hipStream_t stream) {
    const float* features    = (const float*)d_in[0];
    const float* labels      = (const float*)d_in[1];
    const float* label_embed = (const float*)d_in[2];
    const float* gate_w      = (const float*)d_in[3];
    const float* gate_b      = (const float*)d_in[4];
    const float* expert_w    = (const float*)d_in[5];
    const float* expert_b    = (const float*)d_in[6];
    float* out = (float*)d_out;

    // ws layout: Wb bf16 [8][2048][2560] | cb bf16 [1024][2560] | gating f32 |
    //            parts f32 [8][1024][2048]  (parts only on the fast2 path)
    const size_t wb_bytes = (size_t)NEXP * ODIM * INDIM * 2;        // 83,886,080
    const size_t cb_bytes = (size_t)BATCH * INDIM * 2;              //  5,242,880
    const size_t gt_bytes = (size_t)BATCH * NEXP * 4;               //     32,768
    const size_t pt_bytes = (size_t)NEXP * BATCH * ODIM * 4;        // 67,108,864
    const bool fast  = ws_size >= wb_bytes + cb_bytes + gt_bytes;
    const bool fast2 = ws_size >= wb_bytes + cb_bytes + gt_bytes + pt_bytes;

    if (fast) {
        unsigned short* Wb = (unsigned short*)d_ws;
        unsigned short* cb = (unsigned short*)((char*)d_ws + wb_bytes);
        float* gating = (float*)((char*)d_ws + wb_bytes + cb_bytes);
        float* parts  = (float*)((char*)d_ws + wb_bytes + cb_bytes + gt_bytes);
        front_kernel<<<FRONT_BLOCKS, 256, 0, stream>>>(
            expert_w, Wb, features, labels, label_embed, cb, gate_w, gate_b, gating);
        if (fast2) {
            moe_gemm8<false><<<dim3(ODIM / BN, BATCH / BM, NEXP), 512, 0, stream>>>(cb, Wb, gating, expert_b, parts);
            combine_kernel<<<(BATCH * ODIM / 4) / 256, 256, 0, stream>>>(parts, out);
        } else {
            hipMemsetAsync(d_out, 0, (size_t)BATCH * ODIM * sizeof(float), stream);
            moe_gemm8<true><<<dim3(ODIM / BN, BATCH / BM, NEXP), 512, 0, stream>>>(cb, Wb, gating, expert_b, out);
        }
    } else {
        unsigned short* cb = (unsigned short*)d_ws;
        float* gating = (float*)((char*)d_ws + cb_bytes);
        hipMemsetAsync(d_out, 0, (size_t)BATCH * ODIM * sizeof(float), stream);
        prep_kernel<<<BATCH / 4, 256, 0, stream>>>(features, labels, label_embed, cb);
        gate_kernel<<<BATCH, 256, 0, stream>>>(cb, gate_w, gate_b, gating);
        moe_gemm_slow<<<dim3(ODIM / 128, BATCH / 128, NEXP), 256, 0, stream>>>(cb, expert_w, gating, expert_b, out);
    }
}